// Round 9
// baseline (215.257 us; speedup 1.0000x reference)
//
#include <hip/hip_runtime.h>

#define NCLS 19
#define HW (512 * 512)
#define NPIX (8 * HW)
#define TILE 1024                 // pixels per block; 4KB contiguous per channel
#define NBLK (NPIX / TILE)        // 2048 blocks
#define NTHR 1024                 // 16 waves/block; x2 blocks/CU = 32 waves/CU
#define CHUNKS (NCLS * TILE / 4)  // 16B chunks staged per block = 4864

__global__ __launch_bounds__(NTHR, 8) void lms_main_kernel(
    const float* __restrict__ logits, const int* __restrict__ labels,
    float* __restrict__ partials) {
  const float COEFF = 1.0f / 18.0f;  // 1/(C-1)
  const float LAM_HALF = 0.15f;      // 0.3 / 2

  __shared__ float tile[NCLS * TILE];  // 77824 B -> 2 blocks/CU (LDS-limited)

  const int t = threadIdx.x;
  const long pixel0 = (long)blockIdx.x * TILE;
  const int n = blockIdx.x >> 8;              // image (256 blocks per image)
  const int hw0 = (blockIdx.x & 255) * TILE;  // pixel offset within image
  const float* gbase = logits + (size_t)n * NCLS * HW + hw0;

  // ---- stage 19 x 1024 floats via async global->LDS DMA, 16B chunks ----
  // LDS dst = f*16: wave-uniform base + lane*16 (keep linear — R7's rotated
  // dst broke the uniformity proof -> waterfall).
  // aux=2 = CPol NT: non-temporal — single-use streaming data (R8 win).
#pragma unroll
  for (int f = t; f < CHUNKS; f += NTHR) {
    int r = f >> 8;     // channel row (f / 256) — wave-uniform
    int col = f & 255;  // 16B chunk within row
    const float* g = gbase + (size_t)r * HW + col * 4;
    const __attribute__((address_space(1))) float* g1 =
        (const __attribute__((address_space(1))) float*)(uintptr_t)g;
    __attribute__((address_space(3))) float* l3 =
        (__attribute__((address_space(3))) float*)(uintptr_t)(&tile[f * 4]);
    __builtin_amdgcn_global_load_lds(g1, l3, 16, 0, 2);
  }

  int lb = labels[pixel0 + t];
  int l = (lb != 255) ? lb : 0;

  __syncthreads();  // drains vmcnt incl. global_load_lds DMAs

  // ---- compute: 1 pixel/thread from LDS (stride-1 b32, 2 lanes/bank: free) --
  float s = 0.f, T = 0.f, S = 0.f;
#pragma unroll
  for (int c = 0; c < NCLS; ++c) {
    float v = tile[c * TILE + t];
    float e = __expf(v);
    s += e;
    T += e * v;
    S += v;
  }
  float xl = tile[l * TILE + t];

  float el = __expf(xl);
  float sm = s - el;  // masked partition (exact: exp(NEG)=0 in ref)
  float margin = (T - el * xl) / sm - COEFF * (S - xl);
  float ce = __logf(s) - xl;
  bool valid = (lb != 255);
  float loss = valid ? (ce + LAM_HALF * margin) : 0.f;
  float cnt = valid ? 1.f : 0.f;

  // ---- wave (64) shuffle reduction -> block -> per-block partial pair ----
#pragma unroll
  for (int off = 32; off > 0; off >>= 1) {
    loss += __shfl_down(loss, off, 64);
    cnt += __shfl_down(cnt, off, 64);
  }
  __shared__ float sl[16], sc[16];
  int wave = t >> 6;
  int lane = t & 63;
  if (lane == 0) {
    sl[wave] = loss;
    sc[wave] = cnt;
  }
  __syncthreads();
  if (t == 0) {
    float L = 0.f, C = 0.f;
#pragma unroll
    for (int w = 0; w < 16; ++w) {
      L += sl[w];
      C += sc[w];
    }
    partials[2 * blockIdx.x] = L;
    partials[2 * blockIdx.x + 1] = C;
  }
}

__global__ __launch_bounds__(1024) void lms_final_kernel(
    const float* __restrict__ partials, float* __restrict__ out) {
  // 2048 partial pairs; 1024 threads x 2 pairs each
  int t = threadIdx.x;
  float2 a = ((const float2*)partials)[t];
  float2 b = ((const float2*)partials)[t + 1024];
  float loss = a.x + b.x;
  float cnt = a.y + b.y;
#pragma unroll
  for (int off = 32; off > 0; off >>= 1) {
    loss += __shfl_down(loss, off, 64);
    cnt += __shfl_down(cnt, off, 64);
  }
  __shared__ float sl[16], sc[16];
  int wave = t >> 6;
  int lane = t & 63;
  if (lane == 0) {
    sl[wave] = loss;
    sc[wave] = cnt;
  }
  __syncthreads();
  if (t == 0) {
    float L = 0.f, C = 0.f;
#pragma unroll
    for (int w = 0; w < 16; ++w) {
      L += sl[w];
      C += sc[w];
    }
    out[0] = L / C;
  }
}

extern "C" void kernel_launch(void* const* d_in, const int* in_sizes, int n_in,
                              void* d_out, int out_size, void* d_ws, size_t ws_size,
                              hipStream_t stream) {
  const float* logits = (const float*)d_in[0];
  const int* labels = (const int*)d_in[1];
  float* out = (float*)d_out;
  float* partials = (float*)d_ws;  // 2048 x {loss, cnt} = 16 KB

  lms_main_kernel<<<NBLK, NTHR, 0, stream>>>(logits, labels, partials);
  lms_final_kernel<<<1, 1024, 0, stream>>>(partials, out);
}

// Round 11
// 214.278 us; speedup vs baseline: 1.0046x; 1.0046x over previous
//
#include <hip/hip_runtime.h>

#define NCLS 19
#define HW (512 * 512)
#define NPIX (8 * HW)
#define QUADS (NPIX / 4)       // 524288
#define NTHREADS (QUADS / 2)   // 262144: each thread does 2 quads
#define NBLK (NTHREADS / 256)  // 1024 blocks

typedef float vfloat4 __attribute__((ext_vector_type(4)));

__global__ __launch_bounds__(256, 2) void lms_main_kernel(
    const float* __restrict__ logits, const int* __restrict__ labels,
    float* __restrict__ partials) {
  const float COEFF = 1.0f / 18.0f;  // 1/(C-1)
  const float LAM_HALF = 0.15f;      // 0.3 / 2

  const int t = blockIdx.x * 256 + threadIdx.x;
  const long pA = (long)t * 4;               // quad A pixel0
  const long pB = (long)(t + NTHREADS) * 4;  // quad B pixel0

  const float* baseA = logits + (size_t)(pA >> 18) * NCLS * HW + (int)(pA & (HW - 1));
  const float* baseB = logits + (size_t)(pB >> 18) * NCLS * HW + (int)(pB & (HW - 1));

  // ---- issue ALL 38 NT loads before any compute (barrier-free pipeline) ----
  vfloat4 xA[NCLS], xB[NCLS];
#pragma unroll
  for (int c = 0; c < NCLS; ++c)
    xA[c] = __builtin_nontemporal_load((const vfloat4*)(baseA + (size_t)c * HW));
#pragma unroll
  for (int c = 0; c < NCLS; ++c)
    xB[c] = __builtin_nontemporal_load((const vfloat4*)(baseB + (size_t)c * HW));

  int4 lbA = *(const int4*)(labels + pA);
  int4 lbB = *(const int4*)(labels + pB);

  float loss = 0.f, cnt = 0.f;

#define PIXEL(s, T, S, xl, lbv)                           \
  {                                                       \
    float el = __expf(xl);                                \
    float sm = s - el;                                    \
    float margin = (T - el * xl) / sm - COEFF * (S - xl); \
    float ce = __logf(s) - xl;                            \
    bool valid = (lbv != 255);                            \
    loss += valid ? (ce + LAM_HALF * margin) : 0.f;       \
    cnt += valid ? 1.f : 0.f;                             \
  }

#define QUAD(X, LB)                                                \
  {                                                                \
    int l0 = (LB.x != 255) ? LB.x : 0;                             \
    int l1 = (LB.y != 255) ? LB.y : 0;                             \
    int l2 = (LB.z != 255) ? LB.z : 0;                             \
    int l3 = (LB.w != 255) ? LB.w : 0;                             \
    float s0 = 0.f, T0 = 0.f, S0 = 0.f, xl0 = 0.f;                 \
    float s1 = 0.f, T1 = 0.f, S1 = 0.f, xl1 = 0.f;                 \
    float s2 = 0.f, T2 = 0.f, S2 = 0.f, xl2 = 0.f;                 \
    float s3 = 0.f, T3 = 0.f, S3 = 0.f, xl3 = 0.f;                 \
    _Pragma("unroll") for (int c = 0; c < NCLS; ++c) {             \
      vfloat4 v = X[c];                                            \
      float e;                                                     \
      e = __expf(v.x); s0 += e; T0 += e * v.x; S0 += v.x;          \
      xl0 = (c == l0) ? v.x : xl0;                                 \
      e = __expf(v.y); s1 += e; T1 += e * v.y; S1 += v.y;          \
      xl1 = (c == l1) ? v.y : xl1;                                 \
      e = __expf(v.z); s2 += e; T2 += e * v.z; S2 += v.z;          \
      xl2 = (c == l2) ? v.z : xl2;                                 \
      e = __expf(v.w); s3 += e; T3 += e * v.w; S3 += v.w;          \
      xl3 = (c == l3) ? v.w : xl3;                                 \
    }                                                              \
    PIXEL(s0, T0, S0, xl0, LB.x)                                   \
    PIXEL(s1, T1, S1, xl1, LB.y)                                   \
    PIXEL(s2, T2, S2, xl2, LB.z)                                   \
    PIXEL(s3, T3, S3, xl3, LB.w)                                   \
  }

  QUAD(xA, lbA)  // waits only on A's registers; B's loads stay in flight
  QUAD(xB, lbB)
#undef QUAD
#undef PIXEL

  // ---- wave (64) shuffle reduction -> block -> per-block partial pair ----
#pragma unroll
  for (int off = 32; off > 0; off >>= 1) {
    loss += __shfl_down(loss, off, 64);
    cnt += __shfl_down(cnt, off, 64);
  }
  __shared__ float sl[4], sc[4];
  int wave = threadIdx.x >> 6;
  int lane = threadIdx.x & 63;
  if (lane == 0) {
    sl[wave] = loss;
    sc[wave] = cnt;
  }
  __syncthreads();
  if (threadIdx.x == 0) {
    partials[2 * blockIdx.x] = sl[0] + sl[1] + sl[2] + sl[3];
    partials[2 * blockIdx.x + 1] = sc[0] + sc[1] + sc[2] + sc[3];
  }
}

__global__ __launch_bounds__(1024) void lms_final_kernel(
    const float* __restrict__ partials, float* __restrict__ out) {
  // 1024 partial pairs; one per thread
  int t = threadIdx.x;
  float2 pr = ((const float2*)partials)[t];
  float loss = pr.x;
  float cnt = pr.y;
#pragma unroll
  for (int off = 32; off > 0; off >>= 1) {
    loss += __shfl_down(loss, off, 64);
    cnt += __shfl_down(cnt, off, 64);
  }
  __shared__ float sl[16], sc[16];
  int wave = t >> 6;
  int lane = t & 63;
  if (lane == 0) {
    sl[wave] = loss;
    sc[wave] = cnt;
  }
  __syncthreads();
  if (t == 0) {
    float L = 0.f, C = 0.f;
#pragma unroll
    for (int w = 0; w < 16; ++w) {
      L += sl[w];
      C += sc[w];
    }
    out[0] = L / C;
  }
}

extern "C" void kernel_launch(void* const* d_in, const int* in_sizes, int n_in,
                              void* d_out, int out_size, void* d_ws, size_t ws_size,
                              hipStream_t stream) {
  const float* logits = (const float*)d_in[0];
  const int* labels = (const int*)d_in[1];
  float* out = (float*)d_out;
  float* partials = (float*)d_ws;  // 1024 x {loss, cnt} = 8 KB

  lms_main_kernel<<<NBLK, 256, 0, stream>>>(logits, labels, partials);
  lms_final_kernel<<<1, 1024, 0, stream>>>(partials, out);
}